// Round 11
// baseline (473.351 us; speedup 1.0000x reference)
//
#include <hip/hip_runtime.h>
#include <stdint.h>

#define DEV __device__ __forceinline__

typedef __attribute__((ext_vector_type(8))) short short8;   // 8 bf16 = 4 VGPRs
typedef __attribute__((ext_vector_type(4))) float f32x4;

// ---------- helpers ----------
DEV unsigned short f2bf(float f) {
    union { float f; uint32_t u; } v; v.f = f;
    uint32_t u = v.u;
    return (unsigned short)((u + 0x7fffu + ((u >> 16) & 1u)) >> 16);  // RNE
}
DEV float silu_f(float x) { return x / (1.0f + __expf(-x)); }
DEV float softplus_f(float x) { return (x > 20.0f) ? x : log1pf(__expf(x)); }

// token row (0..4095) in fwd-token space for direction-k position l
DEV int tokx(int bk, int l) {            // bk = b*4 + k
    int b = bk >> 2;
    int nn = bk & 1;
    int lf = (bk & 2) ? (1023 - l) : l;  // k>=2 scans the flipped sequence
    return (b * 2 + nn) * 1024 + lf;
}

// degree-3 B-spline bases on uniform grid g[j] = 0.4*(j-3) - 1, j=0..11 -> 8 bases
DEV void bspline8(float x, float* bo) {
    float b[11];
#pragma unroll
    for (int j = 0; j < 11; ++j) {
        float gj  = 0.4f * (float)(j - 3) - 1.0f;
        float gj1 = 0.4f * (float)(j - 2) - 1.0f;
        b[j] = (x >= gj && x < gj1) ? 1.0f : 0.0f;
    }
#pragma unroll
    for (int k = 1; k <= 3; ++k) {
        float inv = 1.0f / (0.4f * (float)k);
#pragma unroll
        for (int j = 0; j + k < 11; ++j) {
            float gj  = 0.4f * (float)(j - 3) - 1.0f;      // g[j]
            float gk1 = 0.4f * (float)(j + k - 2) - 1.0f;  // g[j+k+1]
            b[j] = ((x - gj) * b[j] + (gk1 - x) * b[j + 1]) * inv;
        }
    }
#pragma unroll
    for (int j = 0; j < 8; ++j) bo[j] = b[j];
}

// ---------- weight fold, FEATURE-MAJOR: Wc[o, j*IN+i] (coalesced 16B stores) ----------
__global__ __launch_bounds__(256) void wcFM_kernel(const float* __restrict__ bw,
        const float* __restrict__ sw, const float* __restrict__ sc,
        unsigned short* __restrict__ Wc, int OUT, int IN) {
    int gid = blockIdx.x * 256 + threadIdx.x;      // 8 consecutive i per thread
    int perRow = IN >> 3;
    if (gid >= OUT * perRow) return;
    int o  = gid / perRow;
    int i0 = (gid % perRow) * 8;
    const float* bwp = bw + (size_t)o * IN + i0;
    const float* scp = sc + (size_t)o * IN + i0;
    const float* swp = sw + ((size_t)o * IN + i0) * 8;
    float bwv[8], scv[8], swv[64];
    *(float4*)&bwv[0] = *(const float4*)bwp;
    *(float4*)&bwv[4] = *(const float4*)(bwp + 4);
    *(float4*)&scv[0] = *(const float4*)scp;
    *(float4*)&scv[4] = *(const float4*)(scp + 4);
#pragma unroll
    for (int q = 0; q < 16; ++q) *(float4*)&swv[q * 4] = *(const float4*)(swp + q * 4);
    unsigned short* row = Wc + (size_t)o * 9 * IN + i0;
    short8 v;
#pragma unroll
    for (int e = 0; e < 8; ++e) v[e] = f2bf(bwv[e]);
    *(short8*)row = v;                                  // j = 0 plane
#pragma unroll
    for (int j = 1; j <= 8; ++j) {
#pragma unroll
        for (int e = 0; e < 8; ++e) v[e] = f2bf(swv[e * 8 + (j - 1)] * scv[e]);
        *(short8*)&row[(size_t)j * IN] = v;             // j plane, coalesced
    }
}

// ---------- feature expansion, FEATURE-MAJOR: F[t, j*IN+i] (coalesced) ----------
__global__ __launch_bounds__(256) void featFM_kernel(const float* __restrict__ X,
        unsigned short* __restrict__ F, int ntok, int IN) {
    int gid = blockIdx.x * 256 + threadIdx.x;
    int perRow = IN >> 3;
    if (gid >= ntok * perRow) return;
    int t  = gid / perRow;
    int i0 = (gid % perRow) * 8;
    const float* xp = X + (size_t)t * IN + i0;
    float xv[8];
    *(float4*)&xv[0] = *(const float4*)xp;
    *(float4*)&xv[4] = *(const float4*)(xp + 4);
    float bases[8][8];
    short8 v;
#pragma unroll
    for (int e = 0; e < 8; ++e) {
        v[e] = f2bf(silu_f(xv[e]));
        bspline8(xv[e], bases[e]);
    }
    unsigned short* row = F + (size_t)t * 9 * IN + i0;
    *(short8*)row = v;                                  // j = 0: silu(x)
#pragma unroll
    for (int j = 1; j <= 8; ++j) {
#pragma unroll
        for (int e = 0; e < 8; ++e) v[e] = f2bf(bases[e][j - 1]);
        *(short8*)&row[(size_t)j * IN] = v;
    }
}

// ---------- fused causal conv1d + SiLU -> XSB AND feature-expand -> FEAT2 ----------
// 8 dims per thread; 64 threads (1 wave) per token row.
// NOTE (R10 bug fix): the j=0 feature plane is silu(KAN-input) = silu(xsb),
// i.e. f2bf(silu_f(v8)) — NOT f2bf(v8).
__global__ __launch_bounds__(256) void conv_feat_kernel(const float* __restrict__ xz,
        const float* __restrict__ cw, const float* __restrict__ cb,
        float* __restrict__ xsb, unsigned short* __restrict__ F) {
    int gid = blockIdx.x * 256 + threadIdx.x;     // token*(512/8)
    int tk = gid >> 6;                            // 0..4095 = bn*1024 + l
    int i0 = (gid & 63) * 8;
    int l  = tk & 1023;
    const float* base = xz + (size_t)(tk - l) * 1024 + i0;   // row (bn,0), dims i0..
    float acc[8];
#pragma unroll
    for (int e = 0; e < 8; ++e) acc[e] = cb[i0 + e];
#pragma unroll
    for (int h = 0; h < 4; ++h) {
        int ls = l - 3 + h;
        if (ls >= 0) {
            float xv[8];
            *(float4*)&xv[0] = *(const float4*)(base + (size_t)ls * 1024);
            *(float4*)&xv[4] = *(const float4*)(base + (size_t)ls * 1024 + 4);
#pragma unroll
            for (int e = 0; e < 8; ++e) acc[e] = fmaf(cw[(i0 + e) * 4 + h], xv[e], acc[e]);
        }
    }
    float v8[8];
    float bases[8][8];
    short8 v;
#pragma unroll
    for (int e = 0; e < 8; ++e) {
        v8[e] = silu_f(acc[e]);               // xsb value (input to kan2)
        v[e] = f2bf(silu_f(v8[e]));           // j=0 feature: silu(xsb)  [R10 fix]
        bspline8(v8[e], bases[e]);
    }
    *(float4*)&xsb[(size_t)tk * 512 + i0]     = *(float4*)&v8[0];
    *(float4*)&xsb[(size_t)tk * 512 + i0 + 4] = *(float4*)&v8[4];
    unsigned short* row = F + (size_t)tk * 4608 + i0;
    *(short8*)row = v;
#pragma unroll
    for (int j = 1; j <= 8; ++j) {
#pragma unroll
        for (int e = 0; e < 8; ++e) v[e] = f2bf(bases[e][j - 1]);
        *(short8*)&row[(size_t)j * 512] = v;
    }
}

// ---------- MFMA GEMM, DEPTH=1 pipeline (NB=3), by-fastest XCD chunking ----------
// C[M,N] atomically accumulated over K-chunk bz (C pre-zeroed via memset).
// 256 threads = 4 waves (2x2); per-wave tile (BM/2)x(BN/2); BK=32 (64B rows).
// LDS both-sides XOR swizzle (R5-verified: bank conflicts = 0).
template<int BM, int BN, int DEPTH>
__global__ __launch_bounds__(256) void gemm_mfma2(const unsigned short* __restrict__ A,
        const unsigned short* __restrict__ B, float* __restrict__ C,
        int M, int N, int K, int klen, int gx, int gy, int gz) {
    constexpr int NB  = DEPTH + 2;
    constexpr int FRM = BM / 32;
    constexpr int FRN = BN / 32;
    constexpr int GLA = (BM * 64) / 4096;
    constexpr int GLB = (BN * 64) / 4096;
    constexpr int GL  = GLA + GLB;
    constexpr int LDA = BM * 32;
    constexpr int LDB = BN * 32;
    __shared__ unsigned short As[NB * LDA];
    __shared__ unsigned short Bs[NB * LDB];

    const int nwg = gx * gy * gz;
    int fid = (blockIdx.z * gy + blockIdx.y) * gx + blockIdx.x;
    int cpx = nwg >> 3;
    fid = (fid & 7) * cpx + (fid >> 3);      // XCD-contiguous chunks
    const int by = fid % gy;                 // by fastest: same-XCD shares A panel
    const int bx = (fid / gy) % gx;
    const int bz = fid / (gy * gx);

    const int tid = threadIdx.x;
    const int lane = tid & 63;
    const int w = tid >> 6;
    const int wr = w >> 1, wc = w & 1;
    const int bm = bx * BM, bn = by * BN;
    const int kbase = bz * klen;
    const int NT = klen / 32;
    const int frow = lane & 15;
    const int uq = ((lane >> 4) ^ ((frow >> 1) & 3)) * 8;   // swizzled k-quarter

    f32x4 acc[FRM][FRN];
#pragma unroll
    for (int m = 0; m < FRM; ++m)
#pragma unroll
        for (int n = 0; n < FRN; ++n)
            acc[m][n] = (f32x4){0.f, 0.f, 0.f, 0.f};

    auto stage = [&](int t, int buf) {
        const int k0 = kbase + t * 32;
#pragma unroll
        for (int r = 0; r < GLA; ++r) {
            int bo = r * 4096 + tid * 16;
            int row = bo >> 6;
            int lu = ((bo >> 4) & 3) ^ ((row >> 1) & 3);
            __builtin_amdgcn_global_load_lds(
                (const __attribute__((address_space(1))) void*)((const char*)A + ((size_t)(bm + row) * K + k0) * 2 + lu * 16),
                (__attribute__((address_space(3))) void*)((char*)As + (size_t)buf * LDA * 2 + bo), 16, 0, 0);
        }
#pragma unroll
        for (int r = 0; r < GLB; ++r) {
            int bo = r * 4096 + tid * 16;
            int row = bo >> 6;
            int lu = ((bo >> 4) & 3) ^ ((row >> 1) & 3);
            __builtin_amdgcn_global_load_lds(
                (const __attribute__((address_space(1))) void*)((const char*)B + ((size_t)(bn + row) * K + k0) * 2 + lu * 16),
                (__attribute__((address_space(3))) void*)((char*)Bs + (size_t)buf * LDB * 2 + bo), 16, 0, 0);
        }
    };

    auto compute = [&](int buf) {
        const unsigned short* as = As + (size_t)buf * LDA;
        const unsigned short* bs = Bs + (size_t)buf * LDB;
        short8 af[FRM], bf[FRN];
#pragma unroll
        for (int m = 0; m < FRM; ++m)
            af[m] = *(const short8*)&as[(wr * (BM / 2) + m * 16 + frow) * 32 + uq];
#pragma unroll
        for (int n = 0; n < FRN; ++n)
            bf[n] = *(const short8*)&bs[(wc * (BN / 2) + n * 16 + frow) * 32 + uq];
#pragma unroll
        for (int m = 0; m < FRM; ++m)
#pragma unroll
            for (int n = 0; n < FRN; ++n)
                acc[m][n] = __builtin_amdgcn_mfma_f32_16x16x32_bf16(af[m], bf[n], acc[m][n], 0, 0, 0);
    };

    for (int t = 0; t < DEPTH; ++t) stage(t, t);

    int rb = 0, sb = DEPTH;
    int t = 0;
    for (; t + DEPTH < NT; ++t) {
        stage(t + DEPTH, sb);
        asm volatile("s_waitcnt vmcnt(%0)" :: "i"(DEPTH * GL) : "memory");
        asm volatile("s_barrier" ::: "memory");
        compute(rb);
        rb = (rb + 1 == NB) ? 0 : rb + 1;
        sb = (sb + 1 == NB) ? 0 : sb + 1;
    }
    for (; t < NT; ++t) {
        asm volatile("s_waitcnt vmcnt(0)" ::: "memory");
        asm volatile("s_barrier" ::: "memory");
        compute(rb);
        rb = (rb + 1 == NB) ? 0 : rb + 1;
    }

    // C/D layout: col=lane&15, row=(lane>>4)*4+reg  [m89/m91 verified]
    const int crow = (lane >> 4) * 4;
    const int ccol = lane & 15;
#pragma unroll
    for (int m = 0; m < FRM; ++m)
#pragma unroll
        for (int n = 0; n < FRN; ++n) {
            int gr = bm + wr * (BM / 2) + m * 16 + crow;
            int gc = bn + wc * (BN / 2) + n * 16 + ccol;
#pragma unroll
            for (int r = 0; r < 4; ++r)
                atomicAdd(&C[(size_t)(gr + r) * N + gc], acc[m][n][r]);
        }
}

// ---------- dts = xdbl[:, :32] @ dt_w^T  (no bias/softplus; 4096 fwd tokens) ----------
__global__ __launch_bounds__(256) void dts_kernel(const float* __restrict__ xdbl,
        const float* __restrict__ dtw, float* __restrict__ dts) {
    int t = blockIdx.x >> 1;                 // token 0..4095
    int half = blockIdx.x & 1;
    int d = half * 256 + threadIdx.x;
    __shared__ float dtv[32];
    if (threadIdx.x < 32) dtv[threadIdx.x] = xdbl[(size_t)t * 64 + threadIdx.x];
    __syncthreads();
    const float* w = dtw + (size_t)d * 32;
    float acc = 0.0f;
#pragma unroll
    for (int r = 0; r < 32; r += 4) {
        float4 wv = *(const float4*)(w + r);
        acc = fmaf(dtv[r], wv.x, acc);
        acc = fmaf(dtv[r + 1], wv.y, acc);
        acc = fmaf(dtv[r + 2], wv.z, acc);
        acc = fmaf(dtv[r + 3], wv.w, acc);
    }
    dts[(size_t)t * 512 + d] = acc;
}

// ---------- chunked selective scan: 32 chunks x 32 steps, delta inline ----------
// phase A: per (bk,chunk,d): P = prod a, Q = h_end with h0=0
__global__ __launch_bounds__(256) void scanA_kernel(const float* __restrict__ dts,
        const float* __restrict__ xsb, const float* __restrict__ xdbl,
        const float* __restrict__ A_logs, const float* __restrict__ dtb,
        float* __restrict__ P, float* __restrict__ Q) {
    int half = blockIdx.x & 1;
    int chunk = (blockIdx.x >> 1) & 31;
    int bk = blockIdx.x >> 6;                // 0..7 = b*4+k
    int k = bk & 3;
    int d = half * 256 + threadIdx.x;
    __shared__ float Bl[32][16];
    for (int s = threadIdx.x; s < 32 * 16; s += 256) {
        int ll = s >> 4, n = s & 15;
        Bl[ll][n] = xdbl[(size_t)tokx(bk, chunk * 32 + ll) * 64 + 32 + n];
    }
    __syncthreads();
    float An[16];
#pragma unroll
    for (int n = 0; n < 16; ++n) An[n] = -__expf(A_logs[(size_t)(k * 512 + d) * 16 + n]);
    float bias = dtb[k * 512 + d];
    float h[16] = {};
    float p[16];
#pragma unroll
    for (int n = 0; n < 16; ++n) p[n] = 1.0f;
    for (int ll = 0; ll < 32; ++ll) {
        size_t off = (size_t)tokx(bk, chunk * 32 + ll) * 512 + d;
        float da = softplus_f(dts[off] + bias);
        float du = da * xsb[off];
#pragma unroll
        for (int n = 0; n < 16; ++n) {
            float a = __expf(da * An[n]);
            h[n] = fmaf(h[n], a, du * Bl[ll][n]);
            p[n] *= a;
        }
    }
    size_t pb = ((size_t)(bk * 32 + chunk) * 16) * 512 + d;
#pragma unroll
    for (int n = 0; n < 16; ++n) { P[pb + n * 512] = p[n]; Q[pb + n * 512] = h[n]; }
}

// phase B: serial combine over 32 chunks, parallel over (bk, n) -> 128 blocks
__global__ __launch_bounds__(512) void scanB_kernel(const float* __restrict__ P,
        const float* __restrict__ Q, float* __restrict__ Hst) {
    int bk = blockIdx.x >> 4;
    int n  = blockIdx.x & 15;
    int d  = threadIdx.x;
    float h = 0.0f;
    for (int chunk = 0; chunk < 32; ++chunk) {
        size_t base = ((size_t)((bk * 32 + chunk) * 16 + n)) * 512 + d;
        Hst[base] = h;
        h = fmaf(P[base], h, Q[base]);
    }
}

// phase C: replay with correct h_start, y = h.C + u*D -> ys (scan-position order)
__global__ __launch_bounds__(256) void scanC_kernel(const float* __restrict__ dts,
        const float* __restrict__ xsb, const float* __restrict__ xdbl,
        const float* __restrict__ A_logs, const float* __restrict__ dtb,
        const float* __restrict__ Hst, const float* __restrict__ Ds,
        float* __restrict__ ys) {
    int half = blockIdx.x & 1;
    int chunk = (blockIdx.x >> 1) & 31;
    int bk = blockIdx.x >> 6;
    int k = bk & 3;
    int d = half * 256 + threadIdx.x;
    __shared__ float BC[32][32];             // [ll][0:16]=B, [16:32]=C
    for (int s = threadIdx.x; s < 32 * 32; s += 256) {
        int ll = s >> 5, n = s & 31;
        BC[ll][n] = xdbl[(size_t)tokx(bk, chunk * 32 + ll) * 64 + 32 + n];
    }
    __syncthreads();
    float An[16];
#pragma unroll
    for (int n = 0; n < 16; ++n) An[n] = -__expf(A_logs[(size_t)(k * 512 + d) * 16 + n]);
    float bias = dtb[k * 512 + d];
    float h[16];
    size_t hb = ((size_t)(bk * 32 + chunk) * 16) * 512 + d;
#pragma unroll
    for (int n = 0; n < 16; ++n) h[n] = Hst[hb + n * 512];
    float Dv = Ds[k * 512 + d];
    for (int ll = 0; ll < 32; ++ll) {
        int l = chunk * 32 + ll;
        size_t off = (size_t)tokx(bk, l) * 512 + d;
        float da = softplus_f(dts[off] + bias);
        float u = xsb[off];
        float du = da * u;
        float y = 0.0f;
#pragma unroll
        for (int n = 0; n < 16; ++n) {
            float a = __expf(da * An[n]);
            h[n] = fmaf(h[n], a, du * BC[ll][n]);
            y = fmaf(h[n], BC[ll][16 + n], y);
        }
        ys[((size_t)bk * 1024 + l) * 512 + d] = fmaf(u, Dv, y);
    }
}

// ---------- merge fwd/bwd scans IN-PLACE into xz x-half ----------
__global__ __launch_bounds__(256) void merge_kernel(const float* __restrict__ ys,
        float* __restrict__ xz) {
    int idx = blockIdx.x * 256 + threadIdx.x;   // (b,nn,l,d)
    int d = idx & 511;
    int l = (idx >> 9) & 1023;
    int nn = (idx >> 19) & 1;
    int b = idx >> 20;
    float v = ys[((size_t)(b * 4 + nn) * 1024 + l) * 512 + d]
            + ys[((size_t)(b * 4 + nn + 2) * 1024 + (1023 - l)) * 512 + d];
    size_t trow = (size_t)(b * 2 + nn) * 1024 + l;
    xz[trow * 1024 + d] = v;                    // T3 := [merged_y | z]
}

// ---------- launch ----------
extern "C" void kernel_launch(void* const* d_in, const int* in_sizes, int n_in,
                              void* d_out, int out_size, void* d_ws, size_t ws_size,
                              hipStream_t stream) {
    const float* hidden  = (const float*)d_in[0];
    const float* in_bw   = (const float*)d_in[1];
    const float* in_sw   = (const float*)d_in[2];
    const float* in_sc   = (const float*)d_in[3];
    const float* conv_w  = (const float*)d_in[4];
    const float* conv_b  = (const float*)d_in[5];
    const float* x_bw    = (const float*)d_in[6];
    const float* x_sw    = (const float*)d_in[7];
    const float* x_sc    = (const float*)d_in[8];
    const float* dt_w    = (const float*)d_in[9];
    const float* dt_bias = (const float*)d_in[10];
    const float* A_logs  = (const float*)d_in[11];
    const float* Ds      = (const float*)d_in[12];
    const float* out_bw  = (const float*)d_in[13];
    const float* out_sw  = (const float*)d_in[14];
    const float* out_sc  = (const float*)d_in[15];
    float* out = (float*)d_out;
    char* ws = (char*)d_ws;

    // layout (bytes), peak 120,127,488:
    //   0          XZ   16M (kan1 atomic out -> T3 in-place at merge)
    //  16,777,216  XSB   8M (conv out)
    //  25,165,824  XDBL  1M (4096x64, atomic)
    //  26,214,400  DTS   8M
    //  34,603,008  ZONE 75.5M: FEAT1/FEAT2 @+0 (37.75M); scan YS @+0,
    //     P @+16.8M, Q @+25.2M, HST @+33.6M (after gemm2); FEAT3 @+0 (75.5M)
    // 110,100,480  WCbuf 9.44M (WC1 -> refolded WC3)
    // 119,537,664  WC2  0.56M
    float* XZ    = (float*)(ws + 0);
    float* XSB   = (float*)(ws + 16777216);
    float* XDBL  = (float*)(ws + 25165824);
    float* DTS   = (float*)(ws + 26214400);
    char*  zone  = ws + 34603008;
    unsigned short* FEAT = (unsigned short*)zone;
    float* YS    = (float*)zone;
    float* P     = (float*)(zone + 16777216);
    float* Q     = (float*)(zone + 25165824);
    float* HST   = (float*)(zone + 33554432);
    unsigned short* WCbuf = (unsigned short*)(ws + 110100480);
    unsigned short* WC2   = (unsigned short*)(ws + 119537664);

    // fold weights for kan1, kan2 (feature-major layout)
    wcFM_kernel<<<256, 256, 0, stream>>>(in_bw, in_sw, in_sc, WCbuf, 1024, 512);
    wcFM_kernel<<<16, 256, 0, stream>>>(x_bw, x_sw, x_sc, WC2, 64, 512);

    // kan1: xz = KAN(hidden)   M=4096 N=1024 K=4608, 128x128 split-K x3 atomic
    featFM_kernel<<<1024, 256, 0, stream>>>(hidden, FEAT, 4096, 512);
    hipMemsetAsync(XZ, 0, (size_t)4096 * 1024 * 4, stream);
    gemm_mfma2<128, 128, 1><<<dim3(32, 8, 3), 256, 0, stream>>>(
        FEAT, WCbuf, XZ, 4096, 1024, 4608, 1536, 32, 8, 3);

    // refold WCbuf -> kan3 weights
    wcFM_kernel<<<256, 256, 0, stream>>>(out_bw, out_sw, out_sc, WCbuf, 512, 1024);

    // fused conv + silu -> XSB and feature expansion -> FEAT2
    conv_feat_kernel<<<1024, 256, 0, stream>>>(XZ, conv_w, conv_b, XSB, FEAT);

    // kan2: x_dbl = KAN(xsb)  M=4096 N=64 K=4608, 64x64 split-K x8 atomic
    hipMemsetAsync(XDBL, 0, (size_t)4096 * 64 * 4, stream);
    gemm_mfma2<64, 64, 1><<<dim3(64, 1, 8), 256, 0, stream>>>(
        FEAT, WC2, XDBL, 4096, 64, 4608, 576, 64, 1, 8);

    // dts (pre-softplus; bias+softplus folded into scans per-direction)
    dts_kernel<<<8192, 256, 0, stream>>>(XDBL, dt_w, DTS);

    // chunked selective scan, 32 chunks x 32 steps
    scanA_kernel<<<512, 256, 0, stream>>>(DTS, XSB, XDBL, A_logs, dt_bias, P, Q);
    scanB_kernel<<<128, 512, 0, stream>>>(P, Q, HST);
    scanC_kernel<<<512, 256, 0, stream>>>(DTS, XSB, XDBL, A_logs, dt_bias, HST, Ds, YS);

    // merge into XZ x-half (T3 := XZ)
    merge_kernel<<<8192, 256, 0, stream>>>(YS, XZ);

    // kan3: out = KAN(T3)   M=4096 N=512 K=9216, 128x64 split-K x3 atomic
    featFM_kernel<<<2048, 256, 0, stream>>>(XZ, FEAT, 4096, 1024);
    hipMemsetAsync(out, 0, (size_t)4096 * 512 * 4, stream);
    gemm_mfma2<128, 64, 1><<<dim3(32, 8, 3), 256, 0, stream>>>(
        FEAT, WCbuf, out, 4096, 512, 9216, 3072, 32, 8, 3);
}